// Round 4
// baseline (294.021 us; speedup 1.0000x reference)
//
#include <hip/hip_runtime.h>
#include <hip/hip_bf16.h>

#define B_ 8
#define L_ 2048
#define D_ 128
#define BL_ (B_ * L_)
#define DELTA2 0.016f   // 2*delta, delta = bf16-input dot error bound (2^-7 + accum)

typedef __attribute__((ext_vector_type(8))) short bf16x8;
typedef __attribute__((ext_vector_type(4))) float f32x4;

// ---------------- K1: normalize + bf16 cast + zero repair buffer ----------------
__global__ void k_norm(const float* __restrict__ ctx,
                       float* __restrict__ cn, float* __restrict__ en,
                       ushort* __restrict__ cnb, ushort* __restrict__ enb,
                       unsigned long long* __restrict__ repairbuf) {
    int gtid = blockIdx.x * 256 + threadIdx.x;
    if (gtid < BL_) repairbuf[gtid] = 0ULL;

    int wid  = blockIdx.x * 4 + (threadIdx.x >> 6);   // 0..32767
    int lane = threadIdx.x & 63;
    int b   = wid >> 12;
    int rem = wid & 4095;
    int c   = rem >> 11;
    int l   = rem & 2047;

    const float* src = ctx + (size_t)wid * D_;
    float2 v = ((const float2*)src)[lane];
    float ss = v.x * v.x + v.y * v.y;
    #pragma unroll
    for (int off = 32; off; off >>= 1) ss += __shfl_down(ss, off, 64);
    ss = __shfl(ss, 0, 64);
    float n = fmaxf(sqrtf(ss), 1e-8f);
    float ox = v.x / n, oy = v.y / n;   // true division to match np rounding

    size_t ro = (size_t)(b * L_ + l) * D_;
    float* dst = (c == 0 ? cn : en) + ro;
    ((float2*)dst)[lane] = make_float2(ox, oy);

    __hip_bfloat16 hx = __float2bfloat16(ox), hy = __float2bfloat16(oy);
    ushort ux = *(ushort*)&hx, uy = *(ushort*)&hy;
    ushort* dstb = (c == 0 ? cnb : enb) + ro;
    ((ushort2*)dstb)[lane] = make_ushort2(ux, uy);
}

// ---------------- shared MFMA tile: 64x64 per wave, deterministic ----------------
__device__ __forceinline__ void sim_tile(const ushort* __restrict__ Ab,
                                         const ushort* __restrict__ Bb,
                                         int lane, f32x4 acc[4][4]) {
    int m = lane & 15, q = lane >> 4;
    #pragma unroll
    for (int rt = 0; rt < 4; ++rt)
        #pragma unroll
        for (int ct = 0; ct < 4; ++ct) acc[rt][ct] = (f32x4){0.f, 0.f, 0.f, 0.f};
    #pragma unroll
    for (int kc = 0; kc < 4; ++kc) {
        bf16x8 a[4], bb[4];
        #pragma unroll
        for (int rt = 0; rt < 4; ++rt)
            a[rt] = *(const bf16x8*)(Ab + (size_t)(rt * 16 + m) * D_ + kc * 32 + q * 8);
        #pragma unroll
        for (int ct = 0; ct < 4; ++ct)
            bb[ct] = *(const bf16x8*)(Bb + (size_t)(ct * 16 + m) * D_ + kc * 32 + q * 8);
        #pragma unroll
        for (int rt = 0; rt < 4; ++rt)
            #pragma unroll
            for (int ct = 0; ct < 4; ++ct)
                acc[rt][ct] = __builtin_amdgcn_mfma_f32_16x16x32_bf16(a[rt], bb[ct], acc[rt][ct], 0, 0, 0);
    }
}

// ---------------- K2: bf16 MFMA sim, per-(row, slice) top-2 ----------------
// grid 2048: b = blk&7 (XCD), rb = (blk>>3)&15, cb = blk>>7. Wave = 64x64 tile.
__global__ __launch_bounds__(256) void k_sim(const ushort* __restrict__ cnb,
                                             const ushort* __restrict__ enb,
                                             float4* __restrict__ topt) {
    int bid = blockIdx.x;
    int b = bid & 7, t = bid >> 3, rb = t & 15, cb = t >> 4;
    int wave = threadIdx.x >> 6, lane = threadIdx.x & 63;
    int wr = wave >> 1, wc = wave & 1;
    int row0 = rb * 128 + wr * 64, col0 = cb * 128 + wc * 64;
    const ushort* Ab = cnb + ((size_t)b * L_ + row0) * D_;
    const ushort* Bb = enb + ((size_t)b * L_ + col0) * D_;

    f32x4 acc[4][4];
    sim_tile(Ab, Bb, lane, acc);

    int m = lane & 15, q = lane >> 4;
    int s = cb * 2 + wc;   // slice 0..31, ascending col
    #pragma unroll
    for (int rt = 0; rt < 4; ++rt) {
        #pragma unroll
        for (int reg = 0; reg < 4; ++reg) {
            float v1 = acc[rt][0][reg]; int i1 = col0 + m; float v2 = -3.0e38f;
            #pragma unroll
            for (int ct = 1; ct < 4; ++ct) {
                float v = acc[rt][ct][reg]; int cc = col0 + ct * 16 + m;
                if (v > v1) { v2 = v1; v1 = v; i1 = cc; } else v2 = fmaxf(v2, v);
            }
            #pragma unroll
            for (int msk = 1; msk < 16; msk <<= 1) {
                float V1 = __shfl_xor(v1, msk, 64);
                int   I1 = __shfl_xor(i1, msk, 64);
                float V2 = __shfl_xor(v2, msk, 64);
                if (V1 > v1 || (V1 == v1 && I1 < i1)) { v2 = fmaxf(v1, V2); v1 = V1; i1 = I1; }
                else v2 = fmaxf(v2, V1);
            }
            if (m == 0) {
                int row = row0 + rt * 16 + q * 4 + reg;
                topt[((size_t)s * 8 + b) * L_ + row] = make_float4(v1, __int_as_float(i1), v2, 0.0f);
            }
        }
    }
}

// ---------------- K4: merge slices; certain rows -> finalidx; ambiguous -> exact repair ----------------
__global__ __launch_bounds__(256) void k_repair(const ushort* __restrict__ cnb,
                                                const ushort* __restrict__ enb,
                                                const float4* __restrict__ topt,
                                                const float* __restrict__ cn,
                                                const float* __restrict__ en,
                                                int* __restrict__ finalidx,
                                                int* __restrict__ flagbuf,
                                                unsigned long long* __restrict__ repairbuf) {
    __shared__ float rowth_l[128];
    __shared__ int   rowflag_l[128];
    __shared__ int   anyf;

    int bid = blockIdx.x;
    int b = bid & 7, t = bid >> 3, rb = t & 15, cb = t >> 4;
    int row0blk = rb * 128;
    int tid = threadIdx.x;

    if (tid == 0) anyf = 0;
    __syncthreads();
    if (tid < 128) {
        int row = row0blk + tid;
        float v1 = -3.0e38f, v2 = -3.0e38f; int i1 = 0x7fffffff;
        for (int s = 0; s < 32; ++s) {
            float4 tv = topt[((size_t)s * 8 + b) * L_ + row];
            float V1 = tv.x; int I1 = __float_as_int(tv.y); float V2 = tv.z;
            if (V1 > v1 || (V1 == v1 && I1 < i1)) { v2 = fmaxf(v1, V2); v1 = V1; i1 = I1; }
            else v2 = fmaxf(v2, V1);
        }
        int fl = (v1 - v2 <= DELTA2) ? 1 : 0;
        rowth_l[tid]   = v1 - DELTA2;
        rowflag_l[tid] = fl;
        int gr = b * L_ + row;
        finalidx[gr] = i1;       // 16x duplicated, identical values: benign
        flagbuf[gr]  = fl;
        if (fl) atomicOr(&anyf, 1);
    }
    __syncthreads();
    if (!anyf) return;

    int wave = tid >> 6, lane = tid & 63;
    int wr = wave >> 1, wc = wave & 1;
    int row0 = row0blk + wr * 64, col0 = cb * 128 + wc * 64;
    const ushort* Ab = cnb + ((size_t)b * L_ + row0) * D_;
    const ushort* Bb = enb + ((size_t)b * L_ + col0) * D_;

    f32x4 acc[4][4];
    sim_tile(Ab, Bb, lane, acc);   // identical arithmetic to k_sim -> deterministic

    int m = lane & 15, q = lane >> 4;
    #pragma unroll
    for (int rt = 0; rt < 4; ++rt) {
        #pragma unroll
        for (int ct = 0; ct < 4; ++ct) {
            #pragma unroll
            for (int reg = 0; reg < 4; ++reg) {
                int rl = wr * 64 + rt * 16 + q * 4 + reg;   // 0..127 in block
                if (rowflag_l[rl] && acc[rt][ct][reg] >= rowth_l[rl]) {
                    int col  = col0 + ct * 16 + m;
                    int grow = b * L_ + row0blk + rl;
                    const float* ar = cn + (size_t)grow * D_;
                    const float* br = en + ((size_t)b * L_ + col) * D_;
                    double sd = 0.0;
                    for (int i = 0; i < 32; ++i) {
                        float4 x = ((const float4*)ar)[i];
                        float4 y = ((const float4*)br)[i];
                        sd += (double)x.x * y.x + (double)x.y * y.y
                            + (double)x.z * y.z + (double)x.w * y.w;
                    }
                    long long lb = __double_as_longlong(sd);
                    unsigned long long ub = (unsigned long long)lb;
                    ub = (ub & 0x8000000000000000ULL) ? ~ub : (ub | 0x8000000000000000ULL);
                    ub = (ub & ~0x7FFULL) | (unsigned long long)(2047 - col);
                    atomicMax(repairbuf + grow, ub);
                }
            }
        }
    }
}

// ---------------- K5: g[r] = relu(X[r]@W1+b1)@W2 + b2, fp32, BM=128 8x8 ----------------
__global__ __launch_bounds__(256) void k_feval(
        const float* __restrict__ X,
        const float* __restrict__ W1, const float* __restrict__ b1,
        const float* __restrict__ W2, const float* __restrict__ b2,
        float* __restrict__ g) {
    __shared__ __align__(16) float As[32][132];
    __shared__ __align__(16) float Bs[32][132];
    __shared__ float redv[128][16];

    int tid = threadIdx.x;
    int tx = tid & 15, ty = tid >> 4;
    int r  = tid >> 3, kg = tid & 7;
    int row0 = blockIdx.x * 128;
    const float* Ab = X + (size_t)row0 * D_;

    float acc[8][8];
    #pragma unroll
    for (int i = 0; i < 8; ++i)
        #pragma unroll
        for (int j = 0; j < 8; ++j) acc[i][j] = 0.0f;

    for (int kc = 0; kc < 4; ++kc) {
        __syncthreads();
        #pragma unroll
        for (int p = 0; p < 4; ++p) {
            int rr = r + 32 * p;
            float4 v = *(const float4*)(Ab + (size_t)rr * D_ + kc * 32 + kg * 4);
            As[kg][rr]      = v.x;
            As[8 + kg][rr]  = v.y;
            As[16 + kg][rr] = v.z;
            As[24 + kg][rr] = v.w;
        }
        {
            int kr = r, phys = (kr & 3) * 8 + (kr >> 2);
            const float* srcp = W1 + (size_t)(kc * 32 + kr) * D_ + kg * 16;
            #pragma unroll
            for (int qq = 0; qq < 4; ++qq)
                *(float4*)&Bs[phys][kg * 16 + qq * 4] = *(const float4*)(srcp + qq * 4);
        }
        __syncthreads();
        #pragma unroll
        for (int k = 0; k < 32; ++k) {
            float a[8], bb[8];
            *(float4*)&a[0]  = *(const float4*)&As[k][ty * 4];
            *(float4*)&a[4]  = *(const float4*)&As[k][64 + ty * 4];
            *(float4*)&bb[0] = *(const float4*)&Bs[k][tx * 4];
            *(float4*)&bb[4] = *(const float4*)&Bs[k][64 + tx * 4];
            #pragma unroll
            for (int i = 0; i < 8; ++i)
                #pragma unroll
                for (int j = 0; j < 8; ++j)
                    acc[i][j] = fmaf(a[i], bb[j], acc[i][j]);
        }
    }

    float w2j[8], b1j[8];
    #pragma unroll
    for (int jj = 0; jj < 8; ++jj) {
        int c = (jj < 4) ? (tx * 4 + jj) : (64 + tx * 4 + (jj - 4));
        w2j[jj] = W2[c];
        b1j[jj] = b1[c];
    }
    float bias2 = b2[0];
    __syncthreads();
    #pragma unroll
    for (int i = 0; i < 8; ++i) {
        float s = 0.0f;
        #pragma unroll
        for (int jj = 0; jj < 8; ++jj)
            s += fmaxf(acc[i][jj] + b1j[jj], 0.0f) * w2j[jj];
        int rowl = (i < 4) ? (ty * 4 + i) : (64 + ty * 4 + (i - 4));
        redv[rowl][tx] = s;
    }
    __syncthreads();
    if (tid < 128) {
        float s = 0.0f;
        #pragma unroll
        for (int tt = 0; tt < 16; ++tt) s += redv[tid][tt];
        g[row0 + tid] = s + bias2;
    }
}

// ---------------- K6: output ----------------
__global__ void k_out(const unsigned long long* __restrict__ repairbuf,
                      const int* __restrict__ finalidx, const int* __restrict__ flagbuf,
                      const float* __restrict__ g, float* __restrict__ out) {
    int rr = blockIdx.x * 256 + threadIdx.x;
    if (rr >= BL_) return;
    int b = rr >> 11;
    int idx = flagbuf[rr] ? (2047 - (int)(repairbuf[rr] & 0x7FFULL)) : finalidx[rr];
    out[rr] = g[rr] + g[BL_ + (b << 11) + idx];
}

extern "C" void kernel_launch(void* const* d_in, const int* in_sizes, int n_in,
                              void* d_out, int out_size, void* d_ws, size_t ws_size,
                              hipStream_t stream) {
    const float* context = (const float*)d_in[0];
    const float* W1 = (const float*)d_in[1];
    const float* b1 = (const float*)d_in[2];
    const float* W2 = (const float*)d_in[3];
    const float* b2 = (const float*)d_in[4];
    float* out = (float*)d_out;

    char* ws = (char*)d_ws;
    float*  cn   = (float*)(ws);                         // 8388608 B
    float*  en   = (float*)(ws + 8388608);               // 8388608 B
    ushort* cnb  = (ushort*)(ws + 16777216);             // 4194304 B
    ushort* enb  = (ushort*)(ws + 20971520);             // 4194304 B
    float4* topt = (float4*)(ws + 25165824);             // 8388608 B
    unsigned long long* repairbuf = (unsigned long long*)(ws + 33554432);  // 131072 B
    float*  g    = (float*)(ws + 33685504);              // 131072 B
    int* finalidx = (int*)(ws + 33816576);               // 65536 B
    int* flagbuf  = (int*)(ws + 33882112);               // 65536 B

    k_norm<<<8192, 256, 0, stream>>>(context, cn, en, cnb, enb, repairbuf);
    k_sim<<<2048, 256, 0, stream>>>(cnb, enb, topt);
    k_repair<<<2048, 256, 0, stream>>>(cnb, enb, topt, cn, en, finalidx, flagbuf, repairbuf);
    k_feval<<<256, 256, 0, stream>>>(cn, W1, b1, W2, b2, g);
    k_out<<<BL_ / 256, 256, 0, stream>>>(repairbuf, finalidx, flagbuf, g, out);
}

// Round 5
// 146.606 us; speedup vs baseline: 2.0055x; 2.0055x over previous
//
#include <hip/hip_runtime.h>
#include <hip/hip_bf16.h>

#define B_ 8
#define L_ 2048
#define D_ 128
#define BL_ (B_ * L_)
#define DELTA2 0.016f   // 2*delta; delta=0.008 >= rigorous bf16 dot bound (0.004) with 2x margin
#define QCAP 4096

typedef __attribute__((ext_vector_type(8))) short bf16x8;
typedef __attribute__((ext_vector_type(4))) float f32x4;

// ---------------- K1: normalize + bf16 cast ----------------
__global__ void k_norm(const float* __restrict__ ctx,
                       float* __restrict__ cn, float* __restrict__ en,
                       ushort* __restrict__ cnb, ushort* __restrict__ enb) {
    int wid  = blockIdx.x * 4 + (threadIdx.x >> 6);   // 0..32767
    int lane = threadIdx.x & 63;
    int b   = wid >> 12;
    int rem = wid & 4095;
    int c   = rem >> 11;
    int l   = rem & 2047;

    const float* src = ctx + (size_t)wid * D_;
    float2 v = ((const float2*)src)[lane];
    float ss = v.x * v.x + v.y * v.y;
    #pragma unroll
    for (int off = 32; off; off >>= 1) ss += __shfl_down(ss, off, 64);
    ss = __shfl(ss, 0, 64);
    float n = fmaxf(sqrtf(ss), 1e-8f);
    float ox = v.x / n, oy = v.y / n;

    size_t ro = (size_t)(b * L_ + l) * D_;
    float* dst = (c == 0 ? cn : en) + ro;
    ((float2*)dst)[lane] = make_float2(ox, oy);

    __hip_bfloat16 hx = __float2bfloat16(ox), hy = __float2bfloat16(oy);
    ushort ux = *(ushort*)&hx, uy = *(ushort*)&hy;
    ushort* dstb = (c == 0 ? cnb : enb) + ro;
    ((ushort2*)dstb)[lane] = make_ushort2(ux, uy);
}

// 64x64 bf16 MFMA tile; A fragments from registers, B streamed from global (L2).
__device__ __forceinline__ void tile64(const bf16x8* __restrict__ Areg,
                                       const ushort* __restrict__ Bb,
                                       int m, int q, f32x4 acc[4][4]) {
    #pragma unroll
    for (int rt = 0; rt < 4; ++rt)
        #pragma unroll
        for (int ct = 0; ct < 4; ++ct) acc[rt][ct] = (f32x4){0.f, 0.f, 0.f, 0.f};
    #pragma unroll
    for (int kc = 0; kc < 4; ++kc) {
        bf16x8 bfrag[4];
        #pragma unroll
        for (int ct = 0; ct < 4; ++ct)
            bfrag[ct] = *(const bf16x8*)(Bb + (size_t)(ct * 16 + m) * D_ + kc * 32 + q * 8);
        #pragma unroll
        for (int rt = 0; rt < 4; ++rt)
            #pragma unroll
            for (int ct = 0; ct < 4; ++ct)
                acc[rt][ct] = __builtin_amdgcn_mfma_f32_16x16x32_bf16(
                    Areg[rt * 4 + kc], bfrag[ct], acc[rt][ct], 0, 0, 0);
    }
}

// ---------------- K2: fused sim + argmax + exact repair ----------------
// grid 256 (one block/CU): b = blk&7 (XCD), rb = blk>>3. Block = 64 rows x 2048 cols,
// 8 waves, wave w owns cols [w*256, w*256+256) as 4 tiles of 64x64.
__global__ __launch_bounds__(512) void k_sim(const ushort* __restrict__ cnb,
                                             const ushort* __restrict__ enb,
                                             const float* __restrict__ cn,
                                             const float* __restrict__ en,
                                             int* __restrict__ finalidx) {
    __shared__ float wrowmax[8][64];
    __shared__ float rowth_l[64];
    __shared__ unsigned long long bestw[8][64];
    __shared__ int qbuf[QCAP];
    __shared__ int qn;

    int bid = blockIdx.x;
    int b = bid & 7, rb = bid >> 3;
    int row0 = rb * 64;
    int tid = threadIdx.x;
    int wave = tid >> 6, lane = tid & 63;
    int m = lane & 15, q = lane >> 4;

    if (tid == 0) qn = 0;
    bestw[wave][lane] = 0ULL;

    const ushort* Ab  = cnb + ((size_t)(b * L_) + row0) * D_;
    const ushort* Bb0 = enb + (size_t)(b * L_) * D_;

    // A fragments: 64 rows x 128 k, held in 64 VGPRs for the whole kernel
    bf16x8 Areg[16];
    #pragma unroll
    for (int rt = 0; rt < 4; ++rt)
        #pragma unroll
        for (int kc = 0; kc < 4; ++kc)
            Areg[rt * 4 + kc] = *(const bf16x8*)(Ab + (size_t)(rt * 16 + m) * D_ + kc * 32 + q * 8);

    // ---- phase 1: per-row max over this wave's 1024 entries ----
    float runmax[16];
    #pragma unroll
    for (int s = 0; s < 16; ++s) runmax[s] = -3.0e38f;

    for (int t = 0; t < 4; ++t) {
        f32x4 acc[4][4];
        tile64(Areg, Bb0 + (size_t)(wave * 256 + t * 64) * D_, m, q, acc);
        #pragma unroll
        for (int rt = 0; rt < 4; ++rt)
            #pragma unroll
            for (int reg = 0; reg < 4; ++reg) {
                float v = fmaxf(fmaxf(acc[rt][0][reg], acc[rt][1][reg]),
                                fmaxf(acc[rt][2][reg], acc[rt][3][reg]));
                runmax[rt * 4 + reg] = fmaxf(runmax[rt * 4 + reg], v);
            }
    }
    #pragma unroll
    for (int s = 0; s < 16; ++s) {
        float v = runmax[s];
        v = fmaxf(v, __shfl_xor(v, 1, 64));
        v = fmaxf(v, __shfl_xor(v, 2, 64));
        v = fmaxf(v, __shfl_xor(v, 4, 64));
        v = fmaxf(v, __shfl_xor(v, 8, 64));
        runmax[s] = v;
    }
    if (m == 0) {
        #pragma unroll
        for (int rt = 0; rt < 4; ++rt)
            #pragma unroll
            for (int reg = 0; reg < 4; ++reg)
                wrowmax[wave][rt * 16 + q * 4 + reg] = runmax[rt * 4 + reg];
    }
    __syncthreads();
    if (tid < 64) {
        float rm = wrowmax[0][tid];
        #pragma unroll
        for (int w = 1; w < 8; ++w) rm = fmaxf(rm, wrowmax[w][tid]);
        rowth_l[tid] = rm - DELTA2;
    }
    __syncthreads();
    float rowth_r[16];
    #pragma unroll
    for (int rt = 0; rt < 4; ++rt)
        #pragma unroll
        for (int reg = 0; reg < 4; ++reg)
            rowth_r[rt * 4 + reg] = rowth_l[rt * 16 + q * 4 + reg];

    // ---- phase 2: recompute tiles (MFMA ~free), enqueue candidates >= rowmax - 2*delta ----
    for (int t = 0; t < 4; ++t) {
        int col0 = wave * 256 + t * 64;
        f32x4 acc[4][4];
        tile64(Areg, Bb0 + (size_t)col0 * D_, m, q, acc);
        #pragma unroll
        for (int rt = 0; rt < 4; ++rt)
            #pragma unroll
            for (int reg = 0; reg < 4; ++reg) {
                float th = rowth_r[rt * 4 + reg];
                float mx = fmaxf(fmaxf(acc[rt][0][reg], acc[rt][1][reg]),
                                 fmaxf(acc[rt][2][reg], acc[rt][3][reg]));
                if (mx >= th) {
                    #pragma unroll
                    for (int ct = 0; ct < 4; ++ct)
                        if (acc[rt][ct][reg] >= th) {
                            int pos = atomicAdd(&qn, 1);
                            if (pos < QCAP)
                                qbuf[pos] = ((rt * 16 + q * 4 + reg) << 12) |
                                            (col0 + ct * 16 + m);
                        }
                }
            }
    }
    __syncthreads();

    // ---- phase 3: wave-parallel exact (double) dots for all candidates ----
    int qtot = min(qn, QCAP);
    for (int e = wave; e < qtot; e += 8) {
        int pc = qbuf[e];
        int rl = pc >> 12, col = pc & 0xFFF;
        const float* ar = cn + ((size_t)(b * L_) + row0 + rl) * D_;
        const float* br = en + ((size_t)(b * L_) + col) * D_;
        float2 x = ((const float2*)ar)[lane];
        float2 y = ((const float2*)br)[lane];
        double s = (double)x.x * y.x + (double)x.y * y.y;
        #pragma unroll
        for (int off = 32; off; off >>= 1) s += __shfl_down(s, off, 64);
        if (lane == 0) {
            unsigned long long ub = (unsigned long long)__double_as_longlong(s);
            ub = (ub & 0x8000000000000000ULL) ? ~ub : (ub | 0x8000000000000000ULL);
            ub = (ub & ~0x7FFULL) | (unsigned long long)(2047 - col);  // tie -> lowest col
            if (ub > bestw[wave][rl]) bestw[wave][rl] = ub;            // wave-private, race-free
        }
    }
    __syncthreads();
    if (tid < 64) {
        unsigned long long bb = bestw[0][tid];
        #pragma unroll
        for (int w = 1; w < 8; ++w) { unsigned long long t2 = bestw[w][tid]; if (t2 > bb) bb = t2; }
        finalidx[b * L_ + row0 + tid] = 2047 - (int)(bb & 0x7FFULL);
    }
}

// ---------------- K3: g[r] = relu(X[r]@W1+b1)@W2 + b2, fp32, BM=128 8x8 ----------------
__global__ __launch_bounds__(256) void k_feval(
        const float* __restrict__ X,
        const float* __restrict__ W1, const float* __restrict__ b1,
        const float* __restrict__ W2, const float* __restrict__ b2,
        float* __restrict__ g) {
    __shared__ __align__(16) float As[32][132];
    __shared__ __align__(16) float Bs[32][132];
    __shared__ float redv[128][16];

    int tid = threadIdx.x;
    int tx = tid & 15, ty = tid >> 4;
    int r  = tid >> 3, kg = tid & 7;
    int row0 = blockIdx.x * 128;
    const float* Ab = X + (size_t)row0 * D_;

    float acc[8][8];
    #pragma unroll
    for (int i = 0; i < 8; ++i)
        #pragma unroll
        for (int j = 0; j < 8; ++j) acc[i][j] = 0.0f;

    for (int kc = 0; kc < 4; ++kc) {
        __syncthreads();
        #pragma unroll
        for (int p = 0; p < 4; ++p) {
            int rr = r + 32 * p;
            float4 v = *(const float4*)(Ab + (size_t)rr * D_ + kc * 32 + kg * 4);
            As[kg][rr]      = v.x;
            As[8 + kg][rr]  = v.y;
            As[16 + kg][rr] = v.z;
            As[24 + kg][rr] = v.w;
        }
        {
            int kr = r, phys = (kr & 3) * 8 + (kr >> 2);
            const float* srcp = W1 + (size_t)(kc * 32 + kr) * D_ + kg * 16;
            #pragma unroll
            for (int qq = 0; qq < 4; ++qq)
                *(float4*)&Bs[phys][kg * 16 + qq * 4] = *(const float4*)(srcp + qq * 4);
        }
        __syncthreads();
        #pragma unroll
        for (int k = 0; k < 32; ++k) {
            float a[8], bb[8];
            *(float4*)&a[0]  = *(const float4*)&As[k][ty * 4];
            *(float4*)&a[4]  = *(const float4*)&As[k][64 + ty * 4];
            *(float4*)&bb[0] = *(const float4*)&Bs[k][tx * 4];
            *(float4*)&bb[4] = *(const float4*)&Bs[k][64 + tx * 4];
            #pragma unroll
            for (int i = 0; i < 8; ++i)
                #pragma unroll
                for (int j = 0; j < 8; ++j)
                    acc[i][j] = fmaf(a[i], bb[j], acc[i][j]);
        }
    }

    float w2j[8], b1j[8];
    #pragma unroll
    for (int jj = 0; jj < 8; ++jj) {
        int c = (jj < 4) ? (tx * 4 + jj) : (64 + tx * 4 + (jj - 4));
        w2j[jj] = W2[c];
        b1j[jj] = b1[c];
    }
    float bias2 = b2[0];
    __syncthreads();
    #pragma unroll
    for (int i = 0; i < 8; ++i) {
        float s = 0.0f;
        #pragma unroll
        for (int jj = 0; jj < 8; ++jj)
            s += fmaxf(acc[i][jj] + b1j[jj], 0.0f) * w2j[jj];
        int rowl = (i < 4) ? (ty * 4 + i) : (64 + ty * 4 + (i - 4));
        redv[rowl][tx] = s;
    }
    __syncthreads();
    if (tid < 128) {
        float s = 0.0f;
        #pragma unroll
        for (int tt = 0; tt < 16; ++tt) s += redv[tid][tt];
        g[row0 + tid] = s + bias2;
    }
}

// ---------------- K4: output ----------------
__global__ void k_out(const int* __restrict__ finalidx,
                      const float* __restrict__ g, float* __restrict__ out) {
    int rr = blockIdx.x * 256 + threadIdx.x;
    if (rr >= BL_) return;
    int b = rr >> 11;
    out[rr] = g[rr] + g[BL_ + (b << 11) + finalidx[rr]];
}

extern "C" void kernel_launch(void* const* d_in, const int* in_sizes, int n_in,
                              void* d_out, int out_size, void* d_ws, size_t ws_size,
                              hipStream_t stream) {
    const float* context = (const float*)d_in[0];
    const float* W1 = (const float*)d_in[1];
    const float* b1 = (const float*)d_in[2];
    const float* W2 = (const float*)d_in[3];
    const float* b2 = (const float*)d_in[4];
    float* out = (float*)d_out;

    char* ws = (char*)d_ws;
    float*  cn  = (float*)(ws);                  // 8 MB
    float*  en  = (float*)(ws + 8388608);        // 8 MB
    ushort* cnb = (ushort*)(ws + 16777216);      // 4 MB
    ushort* enb = (ushort*)(ws + 20971520);      // 4 MB
    float*  g   = (float*)(ws + 25165824);       // 128 KB
    int* finalidx = (int*)(ws + 25296896);       // 64 KB

    k_norm<<<8192, 256, 0, stream>>>(context, cn, en, cnb, enb);
    k_sim<<<256, 512, 0, stream>>>(cnb, enb, cn, en, finalidx);
    k_feval<<<256, 256, 0, stream>>>(cn, W1, b1, W2, b2, g);
    k_out<<<BL_ / 256, 256, 0, stream>>>(finalidx, g, out);
}